// Round 2
// baseline (90.201 us; speedup 1.0000x reference)
//
#include <hip/hip_runtime.h>

constexpr int DEPTH      = 10;
constexpr int NUM_TREES  = 64;
constexpr int BATCH      = 2048;
constexpr int NUM_FORKS  = (1 << DEPTH) - 1;   // 1023
constexpr int PAIRS      = BATCH * NUM_TREES;  // 131072
constexpr int WPB        = 4;                  // waves per block
constexpr int REGION     = 1056;               // dword stride per wave LDS region

constexpr float LOG2E = 1.44269504088896340736f;

__global__ __launch_bounds__(256, 4) void ndt_kernel(const float* __restrict__ x,
                                                     float* __restrict__ out) {
    __shared__ float lds[WPB * REGION + 8];
    const int tid  = threadIdx.x;
    const int wave = tid >> 6;
    const int lane = tid & 63;
    const int pair = blockIdx.x * WPB + wave;          // pair = b*64 + t
    const float* __restrict__ xp = x + (size_t)pair * NUM_FORKS;

    // s[q] = x[q-1]; +4/+1 dword shift keeps s[512+8*lane] and s[256+4*lane]
    // 16B-aligned so the leaf/level-8 reads stay ds_read_b128.
    float* s = &lds[wave * REGION + 4];

    // stage 1023 floats, coalesced b32, stride-1 LDS writes (conflict-free)
    #pragma unroll
    for (int m = 0; m < 16; ++m) {
        int f = m * 64 + lane;
        if (m < 15 || f < NUM_FORKS) s[1 + f] = xp[f];
    }
    // No __syncthreads: each wave reads only its own region; DS ops are
    // in-order per wave. Fence only compiler motion:
    __builtin_amdgcn_wave_barrier();

    // ---- levels 9..7 in rational form: subtree value = N/D, one rcp at v7.
    // E = 2^(-x*log2e);  v = (E*N_L*D_R + N_R*D_L) / (D_L*D_R*(1+E))
    float E9[8], D9[8];
    {
        const float4 a = *reinterpret_cast<const float4*>(&s[512 + 8 * lane]);
        const float4 b = *reinterpret_cast<const float4*>(&s[516 + 8 * lane]);
        const float xs[8] = {a.x, a.y, a.z, a.w, b.x, b.y, b.z, b.w};
        #pragma unroll
        for (int c = 0; c < 8; ++c) {
            E9[c] = __builtin_amdgcn_exp2f(-LOG2E * xs[c]);
            D9[c] = 1.0f + E9[c];
        }
    }
    // leaves have N=1, D=1+E9
    float N8[4], D8[4];
    {
        const float4 a = *reinterpret_cast<const float4*>(&s[256 + 4 * lane]);
        const float xs[4] = {a.x, a.y, a.z, a.w};
        #pragma unroll
        for (int d = 0; d < 4; ++d) {
            float E8 = __builtin_amdgcn_exp2f(-LOG2E * xs[d]);
            N8[d] = fmaf(E8, D9[2 * d + 1], D9[2 * d]);
            D8[d] = D9[2 * d] * D9[2 * d + 1] * (1.0f + E8);
        }
    }
    float v7[2];
    #pragma unroll
    for (int e = 0; e < 2; ++e) {
        float E7 = __builtin_amdgcn_exp2f(-LOG2E * s[128 + 2 * lane + e]);
        float N7 = fmaf(E7 * N8[2 * e], D8[2 * e + 1], N8[2 * e + 1] * D8[2 * e]);
        float D7 = D8[2 * e] * D8[2 * e + 1] * (1.0f + E7);
        v7[e] = N7 * __builtin_amdgcn_rcpf(D7);
    }

    // ---- level 6: plain sigmoid lerp (1 rcp) ----
    float E6 = __builtin_amdgcn_exp2f(-LOG2E * s[64 + lane]);
    float s6 = __builtin_amdgcn_rcpf(1.0f + E6);
    float v6 = fmaf(s6, v7[1] - v7[0], v7[0]);

    // ---- path prefix levels 0..5: prefix = rcp( prod(1 + 2^{+-u_i}) ) ----
    float p = 1.0f;
    #pragma unroll
    for (int i = 0; i < 6; ++i) {
        int a = lane >> (6 - i);          // ancestor index at level i
        int b = (lane >> (5 - i)) & 1;    // child bit taken at level i
        float u = LOG2E * s[(1 << i) + a];
        float w = __builtin_amdgcn_exp2f(b ? -u : u);   // b=1: 2^-u -> sigma; b=0: 2^+u -> 1-sigma
        p *= (1.0f + w);
    }
    float v = v6 * __builtin_amdgcn_rcpf(p);

    // ---- wave-wide sum ----
    #pragma unroll
    for (int off = 32; off > 0; off >>= 1) v += __shfl_xor(v, off, 64);
    if (lane == 0) out[pair] = v;
}

extern "C" void kernel_launch(void* const* d_in, const int* in_sizes, int n_in,
                              void* d_out, int out_size, void* d_ws, size_t ws_size,
                              hipStream_t stream) {
    const float* x = (const float*)d_in[0];
    float* out = (float*)d_out;
    dim3 grid(PAIRS / WPB), block(WPB * 64);
    ndt_kernel<<<grid, block, 0, stream>>>(x, out);
}